// Round 12
// baseline (208.695 us; speedup 1.0000x reference)
//
#include <hip/hip_runtime.h>

// GGCARAFE: gradient-guided CARAFE upsample, B=8, C=256, H=W=64, K=3, S=2
// R12 = R7 k_fused verbatim + k_comp jg-split 2 with deep-ILP prefetch:
//   grid 256 x 256thr (1 blk/CU, 1 wave/SIMD), acc[32], 4-stage x8 register
//   dbuf (32 outstanding loads) covers latency without a 2nd wave.
//   x logical traffic 134 -> 67 MB; per-SIMD FMA-issue time unchanged.
// R11 lesson: Phase B lookahead neutral -> compiler already pipelines it.
// ws layout (float indices):
//   w1t   [256][64] f32         @ 0        (16384)   w1t[c*64+j] = w1[j][c]
//   mean  [B][H][W] f32         @ 16384    (32768)
//   w2b   [48][576] bf16        @ 49152    (13824 f32-equiv)  w2b[o][s*64+j]
//   comp_p[8][66][66][64] bf16  @ 62976    (1115136 f32-equiv) zero ring
// total 1,178,112 floats = 4.71 MB

#define W1T_OFF   0
#define MEAN_OFF  16384
#define W2B_OFF   49152
#define CPP_OFF   62976

typedef __attribute__((ext_vector_type(8))) short bf8;            // 8 bf16 = 16B
typedef __attribute__((ext_vector_type(8))) unsigned short us8;   // 16B store
typedef __attribute__((ext_vector_type(4))) float f4;
typedef __attribute__((ext_vector_type(2))) float f2;

static __device__ inline unsigned short f2bf(float f) {
    unsigned u = __float_as_uint(f);
    unsigned r = u + 0x7FFFu + ((u >> 16) & 1u);   // RNE
    return (unsigned short)(r >> 16);
}

// k_init: zero comp_p PAD RING only + weight transposes.
__global__ __launch_bounds__(256) void k_init(const float* __restrict__ w1,
                                              const float* __restrict__ w2,
                                              float* __restrict__ ws) {
    int bid = blockIdx.x, t = threadIdx.x;
    if (bid < 65) {
        int id = bid * 256 + t;           // 0..16639
        if (id < 16640) {
            int px = id >> 3, part = id & 7;
            int b = px / 260, r = px % 260;
            int y, xx;
            if (r < 66)       { y = 0;  xx = r; }
            else if (r < 132) { y = 65; xx = r - 66; }
            else              { int s = r - 132; y = (s & 63) + 1; xx = (s >> 6) ? 65 : 0; }
            uint4* p = (uint4*)((unsigned short*)(ws + CPP_OFF)
                                + ((size_t)(b * 66 + y) * 66 + xx) * 64) + part;
            *p = uint4{0, 0, 0, 0};
        }
        return;
    }
    float* w1t = ws + W1T_OFF;
    unsigned short* w2b = (unsigned short*)(ws + W2B_OFF);
    int gid = (bid - 65) * 256 + t;
    int stride = 68 * 256;
    for (int i = gid; i < 64 * 256; i += stride) {       // w1t[c][j] = w1[j][c]
        int c = i >> 6, j = i & 63;
        w1t[i] = w1[j * 256 + c];
    }
    for (int i = gid; i < 48 * 576; i += stride) {       // w2b[o][s*64+j]
        int o = i / 576, k = i % 576;
        int s = k >> 6, j = k & 63;
        w2b[i] = (o < 36) ? f2bf(w2[o * 576 + j * 9 + s]) : (unsigned short)0;
    }
}

// comp_p[b][h+1][w+1][j] bf16; mean fp32.
// grid 256 x 256: jg = bid>>7 (2 groups of 32 j), pix = (bid&127)*256 + tid.
// bid%8 = pixblock%8 (128 ≡ 0 mod 8) -> both jg copies of a pixblock on the
// same XCD; x logical traffic 2x33.5 MB. 1 wave/SIMD; latency covered by
// 4-stage x 8-deep register prefetch (R8-proven loop body).
__global__ __launch_bounds__(256) void k_comp(const float* __restrict__ x,
                                              const float* __restrict__ b1,
                                              float* __restrict__ ws) {
    const float* w1t = ws + W1T_OFF;
    float* mean = ws + MEAN_OFF;
    unsigned short* cpp = (unsigned short*)(ws + CPP_OFF);
    int jg = blockIdx.x >> 7;                          // uniform 0..1
    int pix = ((blockIdx.x & 127) << 8) + threadIdx.x; // 0..32767
    int b = pix >> 12, hw = pix & 4095;
    int h = hw >> 6, wx = hw & 63;
    const float* xp = x + (size_t)b * 256 * 4096 + hw;
    float acc[32];
#pragma unroll
    for (int jj = 0; jj < 32; jj++) acc[jj] = b1[jg * 32 + jj];
    float msum = 0.f;

    float v0[8], v1[8], v2[8], v3[8];
#pragma unroll
    for (int u = 0; u < 8; u++) v0[u] = xp[(size_t)(u) * 4096];
#pragma unroll
    for (int u = 0; u < 8; u++) v1[u] = xp[(size_t)(8 + u) * 4096];
#pragma unroll
    for (int u = 0; u < 8; u++) v2[u] = xp[(size_t)(16 + u) * 4096];
#pragma unroll
    for (int u = 0; u < 8; u++) v3[u] = xp[(size_t)(24 + u) * 4096];

    for (int c = 0; c < 256; c += 32) {
        // stage 0
#pragma unroll
        for (int u = 0; u < 8; u++) {
            msum += v0[u];
            const float* wp = w1t + (c + u) * 64 + jg * 32;   // uniform -> s_load
#pragma unroll
            for (int jj = 0; jj < 32; jj++) acc[jj] += wp[jj] * v0[u];
        }
        if (c + 32 < 256) {
#pragma unroll
            for (int u = 0; u < 8; u++) v0[u] = xp[(size_t)(c + 32 + u) * 4096];
        }
        // stage 1
#pragma unroll
        for (int u = 0; u < 8; u++) {
            msum += v1[u];
            const float* wp = w1t + (c + 8 + u) * 64 + jg * 32;
#pragma unroll
            for (int jj = 0; jj < 32; jj++) acc[jj] += wp[jj] * v1[u];
        }
        if (c + 40 < 256) {
#pragma unroll
            for (int u = 0; u < 8; u++) v1[u] = xp[(size_t)(c + 40 + u) * 4096];
        }
        // stage 2
#pragma unroll
        for (int u = 0; u < 8; u++) {
            msum += v2[u];
            const float* wp = w1t + (c + 16 + u) * 64 + jg * 32;
#pragma unroll
            for (int jj = 0; jj < 32; jj++) acc[jj] += wp[jj] * v2[u];
        }
        if (c + 48 < 256) {
#pragma unroll
            for (int u = 0; u < 8; u++) v2[u] = xp[(size_t)(c + 48 + u) * 4096];
        }
        // stage 3
#pragma unroll
        for (int u = 0; u < 8; u++) {
            msum += v3[u];
            const float* wp = w1t + (c + 24 + u) * 64 + jg * 32;
#pragma unroll
            for (int jj = 0; jj < 32; jj++) acc[jj] += wp[jj] * v3[u];
        }
        if (c + 56 < 256) {
#pragma unroll
            for (int u = 0; u < 8; u++) v3[u] = xp[(size_t)(c + 56 + u) * 4096];
        }
    }

    unsigned short* dst = cpp + ((size_t)(b * 66 + h + 1) * 66 + (wx + 1)) * 64 + jg * 32;
#pragma unroll
    for (int v = 0; v < 4; v++) {
        us8 o;
#pragma unroll
        for (int jj = 0; jj < 8; jj++) o[jj] = f2bf(acc[v * 8 + jj]);
        *(us8*)(dst + v * 8) = o;
    }
    if (jg == 0) mean[pix] = msum * (1.f / 256.f);
}

// FUSED mask+out (R7 verbatim). grid 512 = (b,h) swizzled; block 384 = 6 waves.
__global__ __launch_bounds__(384) void k_fused(const float* __restrict__ x,
                                               const float* __restrict__ b2,
                                               const float* __restrict__ ws,
                                               float* __restrict__ out) {
    const unsigned short* w2b = (const unsigned short*)(ws + W2B_OFF);
    const unsigned short* cpp = (const unsigned short*)(ws + CPP_OFF);
    const float* mean = ws + MEAN_OFF;
    __shared__ float kern[64][49];   // stride 49: conflict-free epilogue reads
    __shared__ float msk[64][37];    // stride 37: <=2-way on Phase B hoist

    int bid = blockIdx.x;
    int swz = (bid & 7) * 64 + (bid >> 3);             // XCD chunking, bijective
    int b = swz >> 6, h = swz & 63;
    int t = threadIdx.x;
    int wid = __builtin_amdgcn_readfirstlane(t >> 6);  // 0..5, wave-uniform
    int l = t & 63;

    // ---- Phase A: kern GEMM (M=64 px, N=48, K=576) ----
    {
        int o = wid % 3, ph = wid / 3;
        int lm = l & 15, lk = l >> 4;
        bf8 bfrag[18];
        const unsigned short* bp = w2b + (size_t)(o * 16 + lm) * 576 + lk * 8;
#pragma unroll
        for (int ks = 0; ks < 18; ks++) bfrag[ks] = *(const bf8*)(bp + ks * 32);

        const unsigned short* abase = cpp + ((size_t)(b * 66 + h) * 66 + lm) * 64 + lk * 8;
#pragma unroll
        for (int hf = 0; hf < 2; hf++) {
            int w0 = (ph * 2 + hf) * 16;
            const unsigned short* ab = abase + w0 * 64;
            f4 acc = {0.f, 0.f, 0.f, 0.f};
#pragma unroll
            for (int ks = 0; ks < 18; ks++) {
                const int s = ks >> 1, jh = ks & 1;
                const int dy = s / 3, dx = s % 3;          // compile-time
                bf8 af = *(const bf8*)(ab + (dy * 66 + dx) * 64 + jh * 32);
                acc = __builtin_amdgcn_mfma_f32_16x16x32_bf16(af, bfrag[ks], acc, 0, 0, 0);
            }
#pragma unroll
            for (int r = 0; r < 4; r++)
                kern[w0 + lk * 4 + r][o * 16 + lm] = acc[r];
        }
    }
    __syncthreads();

    // grad guidance + softmax -> msk LDS; thread (w, pq) for t < 256
    if (t < 256) {
        int w = t & 63, pq = t >> 6;
        float mc = mean[(b * 64 + h) * 64 + w];
        float v[9], mx = -1e30f;
#pragma unroll
        for (int kk = 0; kk < 9; kk++) {
            int y = h + kk / 3 - 1, xw = w + kk % 3 - 1;
            float mv = ((unsigned)y < 64u && (unsigned)xw < 64u)
                           ? mean[(b * 64 + y) * 64 + xw] : 0.f;
            float d = mv - mc;
            float g = 1.f / (d * d + 0.2f);
            v[kk] = g * (kern[w][kk * 4 + pq] + b2[kk * 4 + pq]);
            mx = fmaxf(mx, v[kk]);
        }
        float s = 0.f;
#pragma unroll
        for (int kk = 0; kk < 9; kk++) { v[kk] = __expf(v[kk] - mx); s += v[kk]; }
        float inv = 1.f / s;
#pragma unroll
        for (int kk = 0; kk < 9; kk++) msk[w][pq * 9 + kk] = v[kk] * inv;
    }
    __syncthreads();

    // ---- Phase B: reassembly, f2 stores ----
    int wv = t >> 6;                 // 0..5: c-slot
    int w = l;

    float m[4][9];
#pragma unroll
    for (int pq = 0; pq < 4; pq++)
#pragma unroll
        for (int kk = 0; kk < 9; kk++) m[pq][kk] = msk[w][pq * 9 + kk];

    for (int c = wv; c < 256; c += 6) {
        const float* xb = x + (size_t)(b * 256 + c) * 4096;
        float p[3][3];
#pragma unroll
        for (int dy = 0; dy < 3; dy++) {
            int y = h + dy - 1;
            bool yok = (unsigned)y < 64u;
#pragma unroll
            for (int dx = 0; dx < 3; dx++) {
                int xx = w + dx - 1;
                p[dy][dx] = (yok && (unsigned)xx < 64u) ? xb[y * 64 + xx] : 0.f;
            }
        }
        float o00 = 0.f, o01 = 0.f, o10 = 0.f, o11 = 0.f;
#pragma unroll
        for (int kk = 0; kk < 9; kk++) {
            float pv = p[kk / 3][kk % 3];
            o00 += pv * m[0][kk];
            o01 += pv * m[1][kk];
            o10 += pv * m[2][kk];
            o11 += pv * m[3][kk];
        }
        float* ob = out + ((size_t)(b * 256 + c) * 128 + 2 * h) * 128 + 2 * w;
        *(f2*)ob = f2{o00, o01};             // row 2h   (p=0)
        *(f2*)(ob + 128) = f2{o10, o11};     // row 2h+1 (p=1)
    }
}

extern "C" void kernel_launch(void* const* d_in, const int* in_sizes, int n_in,
                              void* d_out, int out_size, void* d_ws, size_t ws_size,
                              hipStream_t stream) {
    const float* x  = (const float*)d_in[0];
    const float* w1 = (const float*)d_in[1];
    const float* b1 = (const float*)d_in[2];
    const float* w2 = (const float*)d_in[3];
    const float* b2 = (const float*)d_in[4];
    float* out = (float*)d_out;
    float* ws  = (float*)d_ws;

    k_init<<<133, 256, 0, stream>>>(w1, w2, ws);
    k_comp<<<256, 256, 0, stream>>>(x, b1, ws);
    k_fused<<<512, 384, 0, stream>>>(x, b2, ws, out);
}

// Round 13
// 67.272 us; speedup vs baseline: 3.1023x; 3.1023x over previous
//
#include <hip/hip_runtime.h>

// GGCARAFE: gradient-guided CARAFE upsample, B=8, C=256, H=W=64, K=3, S=2
// R13: k_comp rewritten as MFMA GEMM (M=64px/block, N=64j, K=256c).
//   R12 evidence: scalar-FMA comp is issue/latency-bound (VALUBusy 22%,
//   FETCH only 17MB -> traffic was never the problem). Matrix pipe instead:
//   stage x row -> LDS bf16 (x read ONCE), 32 MFMA/wave, f32 mean local.
// k_fused = R7 verbatim (84.9us baseline component).
// ws layout (float indices):
//   w1bf  [64][256] bf16        @ 0       (8192 f32-equiv)   = bf16(w1[j][c])
//   mean  [B][H][W] f32         @ 8192    (32768)
//   w2b   [48][576] bf16        @ 40960   (13824 f32-equiv)  w2b[o][s*64+j]
//   comp_p[8][66][66][64] bf16  @ 54784   (1115136 f32-equiv) zero ring
// total 1,169,920 floats = 4.68 MB

#define W1BF_OFF  0
#define MEAN_OFF  8192
#define W2B_OFF   40960
#define CPP_OFF   54784

typedef __attribute__((ext_vector_type(8))) short bf8;            // 8 bf16 = 16B
typedef __attribute__((ext_vector_type(8))) unsigned short us8;   // 16B store
typedef __attribute__((ext_vector_type(4))) float f4;
typedef __attribute__((ext_vector_type(2))) float f2;

static __device__ inline unsigned short f2bf(float f) {
    unsigned u = __float_as_uint(f);
    unsigned r = u + 0x7FFFu + ((u >> 16) & 1u);   // RNE
    return (unsigned short)(r >> 16);
}

// k_init: zero comp_p PAD RING only + weight converts/transposes.
__global__ __launch_bounds__(256) void k_init(const float* __restrict__ w1,
                                              const float* __restrict__ w2,
                                              float* __restrict__ ws) {
    int bid = blockIdx.x, t = threadIdx.x;
    if (bid < 65) {
        int id = bid * 256 + t;           // 0..16639
        if (id < 16640) {
            int px = id >> 3, part = id & 7;
            int b = px / 260, r = px % 260;
            int y, xx;
            if (r < 66)       { y = 0;  xx = r; }
            else if (r < 132) { y = 65; xx = r - 66; }
            else              { int s = r - 132; y = (s & 63) + 1; xx = (s >> 6) ? 65 : 0; }
            uint4* p = (uint4*)((unsigned short*)(ws + CPP_OFF)
                                + ((size_t)(b * 66 + y) * 66 + xx) * 64) + part;
            *p = uint4{0, 0, 0, 0};
        }
        return;
    }
    unsigned short* w1bf = (unsigned short*)(ws + W1BF_OFF);
    unsigned short* w2b  = (unsigned short*)(ws + W2B_OFF);
    int gid = (bid - 65) * 256 + t;
    int stride = 68 * 256;
    for (int i = gid; i < 64 * 256; i += stride)         // direct convert
        w1bf[i] = f2bf(w1[i]);
    for (int i = gid; i < 48 * 576; i += stride) {       // w2b[o][s*64+j]
        int o = i / 576, k = i % 576;
        int s = k >> 6, j = k & 63;
        w2b[i] = (o < 36) ? f2bf(w2[o * 576 + j * 9 + s]) : (unsigned short)0;
    }
}

// comp GEMM: comp_p[b][h+1][px+1][j] = bf16(b1[j] + sum_c x[c][px]*w1[j][c]).
// grid 512 = (b,h); block 256 = 4 waves (one 16-j n-tile each).
// Stage: xbf[64px][260c] bf16 via coalesced f4 (x read once); mean f32 local.
// Fragments: identical mapping to k_fused's proven GEMM.
__global__ __launch_bounds__(256) void k_comp(const float* __restrict__ x,
                                              const float* __restrict__ b1,
                                              float* __restrict__ ws) {
    const unsigned short* w1bf = (const unsigned short*)(ws + W1BF_OFF);
    float* mean = ws + MEAN_OFF;
    unsigned short* cpp = (unsigned short*)(ws + CPP_OFF);
    __shared__ unsigned short xbf[64][260];   // 33.3 KB (+4 pad: 2-way reads)
    __shared__ float msp[16][64];             // 4 KB mean partials
    __shared__ float ctile[64][68];           // 17.4 KB epilogue staging

    int bid = blockIdx.x;
    int b = bid >> 6, h = bid & 63;
    int t = threadIdx.x;

    // ---- stage: 16 iters, thread (cg = t>>4, px4 = (t&15)*4) f4 loads ----
    int cg = t >> 4;
    int px4 = (t & 15) * 4;
    float ms0 = 0.f, ms1 = 0.f, ms2 = 0.f, ms3 = 0.f;
    const float* xb = x + (size_t)b * 256 * 4096 + h * 64;
#pragma unroll
    for (int it = 0; it < 16; it++) {
        int c = it * 16 + cg;
        f4 v = *(const f4*)(xb + (size_t)c * 4096 + px4);
        ms0 += v[0]; ms1 += v[1]; ms2 += v[2]; ms3 += v[3];
        xbf[px4 + 0][c] = f2bf(v[0]);
        xbf[px4 + 1][c] = f2bf(v[1]);
        xbf[px4 + 2][c] = f2bf(v[2]);
        xbf[px4 + 3][c] = f2bf(v[3]);
    }
    msp[cg][px4 + 0] = ms0; msp[cg][px4 + 1] = ms1;
    msp[cg][px4 + 2] = ms2; msp[cg][px4 + 3] = ms3;
    __syncthreads();
    if (t < 64) {
        float s = 0.f;
#pragma unroll
        for (int k2 = 0; k2 < 16; k2++) s += msp[k2][t];
        mean[(b * 64 + h) * 64 + t] = s * (1.f / 256.f);
    }

    // ---- MFMA: wave wid = n-tile (16 j); 4 m-tiles x 8 k-steps ----
    int wid = __builtin_amdgcn_readfirstlane(t >> 6);  // 0..3
    int l = t & 63, lm = l & 15, lk = l >> 4;
    bf8 bfrag[8];
    const unsigned short* wp = w1bf + (size_t)(wid * 16 + lm) * 256 + lk * 8;
#pragma unroll
    for (int ks = 0; ks < 8; ks++) bfrag[ks] = *(const bf8*)(wp + ks * 32);
    float bb = b1[wid * 16 + lm];
#pragma unroll
    for (int mt = 0; mt < 4; mt++) {
        f4 acc = {bb, bb, bb, bb};
#pragma unroll
        for (int ks = 0; ks < 8; ks++) {
            bf8 af = *(const bf8*)(&xbf[mt * 16 + lm][ks * 32 + lk * 8]);
            acc = __builtin_amdgcn_mfma_f32_16x16x32_bf16(af, bfrag[ks], acc, 0, 0, 0);
        }
#pragma unroll
        for (int r = 0; r < 4; r++)
            ctile[mt * 16 + lk * 4 + r][wid * 16 + lm] = acc[r];   // C[m][n]
    }
    __syncthreads();

    // ---- epilogue: ctile -> comp_p row h+1, us8x2 per thread ----
    int px = t >> 2, jq = t & 3;
    us8 o0, o1;
#pragma unroll
    for (int i = 0; i < 8; i++) {
        o0[i] = f2bf(ctile[px][jq * 16 + i]);
        o1[i] = f2bf(ctile[px][jq * 16 + 8 + i]);
    }
    unsigned short* dst = cpp + ((size_t)(b * 66 + h + 1) * 66 + (px + 1)) * 64 + jq * 16;
    *(us8*)dst = o0;
    *(us8*)(dst + 8) = o1;
}

// FUSED mask+out (R7 verbatim). grid 512 = (b,h) swizzled; block 384 = 6 waves.
__global__ __launch_bounds__(384) void k_fused(const float* __restrict__ x,
                                               const float* __restrict__ b2,
                                               const float* __restrict__ ws,
                                               float* __restrict__ out) {
    const unsigned short* w2b = (const unsigned short*)(ws + W2B_OFF);
    const unsigned short* cpp = (const unsigned short*)(ws + CPP_OFF);
    const float* mean = ws + MEAN_OFF;
    __shared__ float kern[64][49];   // stride 49: conflict-free epilogue reads
    __shared__ float msk[64][37];    // stride 37: <=2-way on Phase B hoist

    int bid = blockIdx.x;
    int swz = (bid & 7) * 64 + (bid >> 3);             // XCD chunking, bijective
    int b = swz >> 6, h = swz & 63;
    int t = threadIdx.x;
    int wid = __builtin_amdgcn_readfirstlane(t >> 6);  // 0..5, wave-uniform
    int l = t & 63;

    // ---- Phase A: kern GEMM (M=64 px, N=48, K=576) ----
    {
        int o = wid % 3, ph = wid / 3;
        int lm = l & 15, lk = l >> 4;
        bf8 bfrag[18];
        const unsigned short* bp = w2b + (size_t)(o * 16 + lm) * 576 + lk * 8;
#pragma unroll
        for (int ks = 0; ks < 18; ks++) bfrag[ks] = *(const bf8*)(bp + ks * 32);

        const unsigned short* abase = cpp + ((size_t)(b * 66 + h) * 66 + lm) * 64 + lk * 8;
#pragma unroll
        for (int hf = 0; hf < 2; hf++) {
            int w0 = (ph * 2 + hf) * 16;
            const unsigned short* ab = abase + w0 * 64;
            f4 acc = {0.f, 0.f, 0.f, 0.f};
#pragma unroll
            for (int ks = 0; ks < 18; ks++) {
                const int s = ks >> 1, jh = ks & 1;
                const int dy = s / 3, dx = s % 3;          // compile-time
                bf8 af = *(const bf8*)(ab + (dy * 66 + dx) * 64 + jh * 32);
                acc = __builtin_amdgcn_mfma_f32_16x16x32_bf16(af, bfrag[ks], acc, 0, 0, 0);
            }
#pragma unroll
            for (int r = 0; r < 4; r++)
                kern[w0 + lk * 4 + r][o * 16 + lm] = acc[r];
        }
    }
    __syncthreads();

    // grad guidance + softmax -> msk LDS; thread (w, pq) for t < 256
    if (t < 256) {
        int w = t & 63, pq = t >> 6;
        float mc = mean[(b * 64 + h) * 64 + w];
        float v[9], mx = -1e30f;
#pragma unroll
        for (int kk = 0; kk < 9; kk++) {
            int y = h + kk / 3 - 1, xw = w + kk % 3 - 1;
            float mv = ((unsigned)y < 64u && (unsigned)xw < 64u)
                           ? mean[(b * 64 + y) * 64 + xw] : 0.f;
            float d = mv - mc;
            float g = 1.f / (d * d + 0.2f);
            v[kk] = g * (kern[w][kk * 4 + pq] + b2[kk * 4 + pq]);
            mx = fmaxf(mx, v[kk]);
        }
        float s = 0.f;
#pragma unroll
        for (int kk = 0; kk < 9; kk++) { v[kk] = __expf(v[kk] - mx); s += v[kk]; }
        float inv = 1.f / s;
#pragma unroll
        for (int kk = 0; kk < 9; kk++) msk[w][pq * 9 + kk] = v[kk] * inv;
    }
    __syncthreads();

    // ---- Phase B: reassembly, f2 stores ----
    int wv = t >> 6;                 // 0..5: c-slot
    int w = l;

    float m[4][9];
#pragma unroll
    for (int pq = 0; pq < 4; pq++)
#pragma unroll
        for (int kk = 0; kk < 9; kk++) m[pq][kk] = msk[w][pq * 9 + kk];

    for (int c = wv; c < 256; c += 6) {
        const float* xb = x + (size_t)(b * 256 + c) * 4096;
        float p[3][3];
#pragma unroll
        for (int dy = 0; dy < 3; dy++) {
            int y = h + dy - 1;
            bool yok = (unsigned)y < 64u;
#pragma unroll
            for (int dx = 0; dx < 3; dx++) {
                int xx = w + dx - 1;
                p[dy][dx] = (yok && (unsigned)xx < 64u) ? xb[y * 64 + xx] : 0.f;
            }
        }
        float o00 = 0.f, o01 = 0.f, o10 = 0.f, o11 = 0.f;
#pragma unroll
        for (int kk = 0; kk < 9; kk++) {
            float pv = p[kk / 3][kk % 3];
            o00 += pv * m[0][kk];
            o01 += pv * m[1][kk];
            o10 += pv * m[2][kk];
            o11 += pv * m[3][kk];
        }
        float* ob = out + ((size_t)(b * 256 + c) * 128 + 2 * h) * 128 + 2 * w;
        *(f2*)ob = f2{o00, o01};             // row 2h   (p=0)
        *(f2*)(ob + 128) = f2{o10, o11};     // row 2h+1 (p=1)
    }
}

extern "C" void kernel_launch(void* const* d_in, const int* in_sizes, int n_in,
                              void* d_out, int out_size, void* d_ws, size_t ws_size,
                              hipStream_t stream) {
    const float* x  = (const float*)d_in[0];
    const float* w1 = (const float*)d_in[1];
    const float* b1 = (const float*)d_in[2];
    const float* w2 = (const float*)d_in[3];
    const float* b2 = (const float*)d_in[4];
    float* out = (float*)d_out;
    float* ws  = (float*)d_ws;

    k_init<<<133, 256, 0, stream>>>(w1, w2, ws);
    k_comp<<<512, 256, 0, stream>>>(x, b1, ws);
    k_fused<<<512, 384, 0, stream>>>(x, b2, ws, out);
}